// Round 8
// baseline (16440.097 us; speedup 1.0000x reference)
//
#include <hip/hip_runtime.h>

// ---------------- problem constants ----------------
// B=512, T=128, H=512, ZT=64, GRU_IN=579
// 256 wgs = 16 groups (32 rows) x 16 slices (32 units = 96 gate cols)
// block = 1024 threads = 16 waves = kh(4 K-quarters) x rv(4 row-quarters).
// lane: pr = lane&15 -> unit pair {pr, pr+16}; rs = lane>>4 -> rows {rv*8+2rs, +1}.
// acc[pair][row][gate] = 12 regs. 4-deep k-split reduced via 3-sync LDS ladder.
// FUSED gemm: [Wih1 | Whh0] share one A-pass (gi1(t) + gh0(t+1)) — h0_new is
// the A for both. B panels gate/pair-packed for lane-contiguous 256B bursts.

// ---- ws layout (float element offsets) ----
#define OFF_HID    0u        // [512][512]
#define OFF_BASE   262144u   // [512][512] baseline
#define OFF_WFUSE  524288u   // [16][256 k2][2 panel][3 gate][16 pr][2 pair][2 ki]
#define OFF_WHH1P  2097152u  // [16][128 k4][3 gate][2 pair][16 pr][4 ki] Whh1
#define OFF_WMIDP  2883584u  // [16][96][512] Wih0 rows 64..575 (for gi0_kernel)
#define OFF_WTOPP  3670016u  // [16][16 k4][3][2][16][4] Wih0 rows 0..63
#define OFF_CELLC  3768320u  // [16][32 unit][20] cell constants
#define OFF_GI0S   3778560u  // [16][512 row][32 unit][4] baseline@Wmid + bih0
#define OFF_H0X    4827136u  // [512][512] h0 exchange
#define OFF_H1X    5089280u  // [512][512] h1 exchange
#define OFF_HWTC   5351424u  // [24][512] W_tc^T
#define OFF_HWHZ   5363712u  // [2][516]  W_hz rows (col 512 = t coef, pad)
#define OFF_HWT0   5364752u  // [6][512]  W_tcat0^T
#define OFF_HWT2   5367824u  // [10][512] W_tcat2^T
#define OFF_HWT4   5372944u  // [4][512]  W_tcat4^T
#define OFF_IRR0   5374992u  // [512][2]
#define OFF_CTR    5376016u  // 16 groups x 32 u32 barrier counters
#define OFF_END    5376528u

// ---- out layout (flat concat, reference return order) ----
#define OUT_SC   0u
#define OUT_SCAT 8192u
#define OUT_TC   20992u
#define OUT_TCAT 1593856u
#define OUT_VM   3035648u
#define OUT_VT   3101184u

#define AS 516   // A row stride (pad 4)
#define RS 97    // partial-buffer row stride

__device__ __forceinline__ float sigm(float x) { return 1.0f / (1.0f + expf(-x)); }
__device__ __forceinline__ float gumb(float u) { return -logf(-logf(u + 1e-10f) + 1e-10f); }
__device__ __forceinline__ float dot4(float4 a, float4 b) {
  return fmaf(a.x, b.x, fmaf(a.y, b.y, fmaf(a.z, b.z, a.w * b.w)));
}
__device__ __forceinline__ void astore(float* p, float v) {
  __hip_atomic_store(p, v, __ATOMIC_RELAXED, __HIP_MEMORY_SCOPE_AGENT);
}

// ---------------- weight packing ----------------
__global__ __launch_bounds__(256) void pack_kernel(
    const float* __restrict__ Wih0, const float* __restrict__ Whh0,
    const float* __restrict__ Wih1, const float* __restrict__ Whh1,
    const float* __restrict__ bhh0, const float* __restrict__ bih1,
    const float* __restrict__ bhh1,
    const float* __restrict__ W_tc, const float* __restrict__ W_hz,
    const float* __restrict__ W_tcat0, const float* __restrict__ W_tcat2,
    const float* __restrict__ W_tcat4, float* __restrict__ ws) {
  int idx = blockIdx.x * 256 + threadIdx.x;
  if (idx < 1572864) {  // WFUSE [k2][panel][gate][pr][pair][ki2]
    int s = idx / 98304, t = idx % 98304;
    int k2 = t / 384, rem = t % 384;
    int panel = rem / 192, rem2 = rem % 192;
    int gate = rem2 / 64, rem3 = rem2 % 64;
    int pr = rem3 >> 2, q = rem3 & 3;
    int pair = q >> 1, ki = q & 1;
    int k = 2 * k2 + ki;
    int col = gate * 512 + s * 32 + pair * 16 + pr;
    ws[OFF_WFUSE + (unsigned)idx] = panel ? Whh0[k * 1536 + col] : Wih1[k * 1536 + col];
    return;
  }
  idx -= 1572864;
  if (idx < 786432) {  // WpH (Whh1) [k4][gate][pair][pr][ki4]
    int s = idx / 49152, t = idx % 49152;
    int k4 = t / 384, rem = t % 384;
    int gate = rem / 128, rem2 = rem % 128;
    int pair = rem2 / 64, rem3 = rem2 % 64;
    int pr = rem3 >> 2, ki = rem3 & 3;
    int k = 4 * k4 + ki;
    int col = gate * 512 + s * 32 + pair * 16 + pr;
    ws[OFF_WHH1P + (unsigned)idx] = Whh1[k * 1536 + col];
    return;
  }
  idx -= 786432;
  if (idx < 786432) {  // WMIDP (unchanged layout, for gi0_kernel)
    int s = idx / 49152, t = idx % 49152;
    int c = t / 512, k = t % 512;
    int col = (c % 3) * 512 + s * 32 + c / 3;
    ws[OFF_WMIDP + (unsigned)idx] = Wih0[(64 + k) * 1536 + col];
    return;
  }
  idx -= 786432;
  if (idx < 98304) {  // WpT [k4<16][gate][pair][pr][ki4]
    int s = idx / 6144, t = idx % 6144;
    int k4 = t / 384, rem = t % 384;
    int gate = rem / 128, rem2 = rem % 128;
    int pair = rem2 / 64, rem3 = rem2 % 64;
    int pr = rem3 >> 2, ki = rem3 & 3;
    int k = 4 * k4 + ki;
    int col = gate * 512 + s * 32 + pair * 16 + pr;
    ws[OFF_WTOPP + (unsigned)idx] = Wih0[k * 1536 + col];
    return;
  }
  idx -= 98304;
  if (idx < 10240) {  // CELLC [s][unit][20]
    int s = idx / 640, rem = idx % 640;
    int unit = rem / 20, q = rem % 20;
    int base = s * 32 + unit;
    float v = 0.0f;
    if (q < 3)       v = Wih0[576 * 1536 + q * 512 + base];
    else if (q < 6)  v = Wih0[577 * 1536 + (q - 3) * 512 + base];
    else if (q < 9)  v = Wih0[578 * 1536 + (q - 6) * 512 + base];
    else if (q < 12) v = bhh0[(q - 9) * 512 + base];
    else if (q < 15) v = bih1[(q - 12) * 512 + base];
    else if (q < 18) v = bhh1[(q - 15) * 512 + base];
    ws[OFF_CELLC + (unsigned)idx] = v;
    return;
  }
  idx -= 10240;
  if (idx < 12288) { int c = idx / 512, k = idx % 512; ws[OFF_HWTC + (unsigned)idx] = W_tc[k * 24 + c]; return; }
  idx -= 12288;
  if (idx < 1032) {
    int c = idx / 516, j = idx % 516;
    ws[OFF_HWHZ + (unsigned)idx] = (j < 513) ? W_hz[c * 513 + j] : 0.0f;
    return;
  }
  idx -= 1032;
  if (idx < 3072) { int c = idx / 512, k = idx % 512; ws[OFF_HWT0 + (unsigned)idx] = W_tcat0[k * 6 + c]; return; }
  idx -= 3072;
  if (idx < 5120) { int c = idx / 512, k = idx % 512; ws[OFF_HWT2 + (unsigned)idx] = W_tcat2[k * 10 + c]; return; }
  idx -= 5120;
  if (idx < 2048) { int c = idx / 512, k = idx % 512; ws[OFF_HWT4 + (unsigned)idx] = W_tcat4[k * 4 + c]; }
}

// ---------------- static MLP ----------------
template <int K>
__global__ __launch_bounds__(256) void mlp_kernel(
    const float* __restrict__ X, const float* __restrict__ Wm,
    const float* __restrict__ bias, float* __restrict__ Y) {
  __shared__ float Xs[4][K];
  const int rt = blockIdx.x, tid = threadIdx.x;
  for (int i = tid; i < 4 * K; i += 256) Xs[i / K][i % K] = X[(rt * 4 + i / K) * K + (i % K)];
  __syncthreads();
  float acc[4][2] = {};
  const int c0 = tid, c1 = tid + 256;
  for (int k = 0; k < K; ++k) {
    float w0 = Wm[k * 512 + c0], w1 = Wm[k * 512 + c1];
#pragma unroll
    for (int r = 0; r < 4; ++r) {
      acc[r][0] = fmaf(Xs[r][k], w0, acc[r][0]);
      acc[r][1] = fmaf(Xs[r][k], w1, acc[r][1]);
    }
  }
#pragma unroll
  for (int r = 0; r < 4; ++r) {
    Y[(rt * 4 + r) * 512 + c0] = fmaxf(acc[r][0] + bias[c0], 0.0f);
    Y[(rt * 4 + r) * 512 + c1] = fmaxf(acc[r][1] + bias[c1], 0.0f);
  }
}

// ---------------- gi0 static part (output layout: [s][row][unit][4]) ----------------
__global__ __launch_bounds__(256) void gi0_kernel(
    const float* __restrict__ baseline, const float* __restrict__ WmidP,
    const float* __restrict__ bih0, float* __restrict__ gi0s) {
  __shared__ float As[64][128];
  __shared__ float Bs[96][129];
  const int s = blockIdx.x >> 3, rt = blockIdx.x & 7;
  const int tid = threadIdx.x, cg = tid & 31, rg = tid >> 5;
  float acc[8][3] = {};
  for (int kc = 0; kc < 4; ++kc) {
    for (int i = tid; i < 2048; i += 256) {
      int r = i >> 5, k4 = (i & 31) << 2;
      *(float4*)&As[r][k4] = *(const float4*)&baseline[(rt * 64 + r) * 512 + kc * 128 + k4];
    }
    for (int i = tid; i < 3072; i += 256) {
      int c = i >> 5, k4 = (i & 31) << 2;
      float4 v = *(const float4*)&WmidP[((unsigned)s * 96 + c) * 512 + kc * 128 + k4];
      Bs[c][k4] = v.x; Bs[c][k4 + 1] = v.y; Bs[c][k4 + 2] = v.z; Bs[c][k4 + 3] = v.w;
    }
    __syncthreads();
    for (int kk = 0; kk < 128; ++kk) {
      float b0 = Bs[3 * cg + 0][kk], b1 = Bs[3 * cg + 1][kk], b2 = Bs[3 * cg + 2][kk];
#pragma unroll
      for (int r = 0; r < 8; ++r) {
        float a = As[rg * 8 + r][kk];
        acc[r][0] = fmaf(a, b0, acc[r][0]);
        acc[r][1] = fmaf(a, b1, acc[r][1]);
        acc[r][2] = fmaf(a, b2, acc[r][2]);
      }
    }
    __syncthreads();
  }
#pragma unroll
  for (int r = 0; r < 8; ++r)
#pragma unroll
    for (int j = 0; j < 3; ++j) {
      gi0s[(((unsigned)s * 512 + rt * 64 + rg * 8 + r) * 32 + cg) * 4 + j] =
          acc[r][j] + bih0[j * 512 + s * 32 + cg];
    }
}

// ---------------- static heads ----------------
__device__ void gumbel_write(const float* logits, int w, const float* u, float* dst) {
  float e[12]; float mx = -1e30f;
#pragma unroll
  for (int i = 0; i < 12; ++i) if (i < w) { e[i] = logits[i] + gumb(u[i]); mx = fmaxf(mx, e[i]); }
  float sum = 0.0f;
#pragma unroll
  for (int i = 0; i < 12; ++i) if (i < w) { e[i] = expf(e[i] - mx); sum += e[i]; }
  float inv = 1.0f / sum;
#pragma unroll
  for (int i = 0; i < 12; ++i) if (i < w) dst[i] = e[i] * inv;
}

__global__ __launch_bounds__(64) void static_heads_kernel(
    const float* __restrict__ baseline,
    const float* __restrict__ W_sc, const float* __restrict__ b_sc,
    const float* __restrict__ W_cat0, const float* __restrict__ b_cat0,
    const float* __restrict__ W_cat1, const float* __restrict__ b_cat1,
    const float* __restrict__ W_cat2, const float* __restrict__ b_cat2,
    const float* __restrict__ W_irr, const float* __restrict__ b_irr,
    const float* __restrict__ u_sc0, const float* __restrict__ u_sc1,
    const float* __restrict__ u_sc2, const float* __restrict__ u_irr,
    float* __restrict__ out, float* __restrict__ irr0buf) {
  const int b = blockIdx.x, tid = threadIdx.x;
  __shared__ float br[512];
  __shared__ float dots[48];
  for (int i = tid; i < 512; i += 64) br[i] = baseline[b * 512 + i];
  __syncthreads();
  if (tid < 45) {
    float d = 0.0f;
    if (tid < 16) { for (int k = 0; k < 512; ++k) d = fmaf(br[k], W_sc[k * 16 + tid], d); d += b_sc[tid]; }
    else if (tid < 24) { int c = tid - 16; for (int k = 0; k < 512; ++k) d = fmaf(br[k], W_cat0[k * 8 + c], d); d += b_cat0[c]; }
    else if (tid < 29) { int c = tid - 24; for (int k = 0; k < 512; ++k) d = fmaf(br[k], W_cat1[k * 5 + c], d); d += b_cat1[c]; }
    else if (tid < 41) { int c = tid - 29; for (int k = 0; k < 512; ++k) d = fmaf(br[k], W_cat2[k * 12 + c], d); d += b_cat2[c]; }
    else { int i = tid - 41, j = i >> 1, cls = i & 1;
           for (int k = 0; k < 512; ++k) d = fmaf(br[k], W_irr[j * 1024 + k * 2 + cls], d);
           d += b_irr[j * 2 + cls]; }
    dots[tid] = d;
  }
  __syncthreads();
  if (tid < 16) out[OUT_SC + b * 16 + tid] = sigm(dots[tid]);
  else if (tid == 16) gumbel_write(&dots[16], 8,  u_sc0 + b * 8,  out + OUT_SCAT + b * 25 + 0);
  else if (tid == 17) gumbel_write(&dots[24], 5,  u_sc1 + b * 5,  out + OUT_SCAT + b * 25 + 8);
  else if (tid == 18) gumbel_write(&dots[29], 12, u_sc2 + b * 12, out + OUT_SCAT + b * 25 + 13);
  else if (tid == 19 || tid == 20) {
    int j = tid - 19;
    float e0 = dots[41 + 2 * j] + gumb(u_irr[j * 1024 + b * 2 + 0]);
    float e1 = dots[42 + 2 * j] + gumb(u_irr[j * 1024 + b * 2 + 1]);
    float mx = fmaxf(e0, e1);
    float x0 = expf(e0 - mx), x1 = expf(e1 - mx);
    irr0buf[b * 2 + j] = x1 / (x0 + x1);
  }
}

// ---------------- persistent recurrence kernel ----------------
__global__ __launch_bounds__(1024, 4) void recurrence_kernel(
    float* ws, const float* __restrict__ z_temporal, const int* __restrict__ lengths,
    const float* __restrict__ b_tc, const float* __restrict__ b_hz,
    const float* __restrict__ b_tcat0, const float* __restrict__ b_tcat2,
    const float* __restrict__ b_tcat4,
    const float* __restrict__ u_t0, const float* __restrict__ u_t2,
    const float* __restrict__ u_t4, const float* __restrict__ u_bern,
    float* __restrict__ out) {
  const int tid = threadIdx.x;
  const int s = blockIdx.x & 15;   // slice -> XCD-pinned
  const int g = blockIdx.x >> 4;   // batch group
  const int b0 = g * 32;
  // gemm roles: 16 waves = kh(4 K-quarters) x rv(4 row-quarters)
  const int lane = tid & 63, wv = tid >> 6;
  const int kh = wv >> 2;          // K quarter [128kh, 128kh+128)
  const int rv = wv & 3;           // row quarter [8rv, 8rv+8)
  const int pr = lane & 15;        // unit pair -> units {pr, pr+16}
  const int rs = lane >> 4;        // row sub
  const int r0 = rv * 8 + rs * 2;  // lane rows: r0, r0+1
  // heads role: 32 rows x 32 k-lanes
  const int hrow = tid >> 5, kp = tid & 31;

  __shared__ __align__(16) float A0[32 * AS];
  __shared__ __align__(16) float A1[32 * AS];
  __shared__ __align__(16) float Rbuf[2 * 32 * RS];
  __shared__ float irr_l[32][2];

  float* h0x = ws + OFF_H0X;
  float* h1x = ws + OFF_H1X;
  unsigned* ctr = ((unsigned*)(ws + OFF_CTR)) + g * 32;

  const float* WpF = ws + OFF_WFUSE + (unsigned)s * 98304;
  const float* WpH = ws + OFF_WHH1P + (unsigned)s * 49152;
  const float* WpT = ws + OFF_WTOPP + (unsigned)s * 6144;
  const float* cellc = ws + OFF_CELLC + (unsigned)s * 640;
  const float* gi0p = ws + OFF_GI0S + ((unsigned)s * 512 + b0) * 128;
  float bhz0 = b_hz[0], bhz1 = b_hz[1];

  // init
  for (int i = tid; i < 32 * AS; i += 1024) { A0[i] = 0.0f; A1[i] = 0.0f; }
  if (tid < 64) irr_l[tid >> 1][tid & 1] = ws[OFF_IRR0 + (b0 + (tid >> 1)) * 2 + (tid & 1)];
  __syncthreads();

  // split-phase group barrier
  unsigned bart = 0;
  auto barrive = [&]() {
    __builtin_amdgcn_s_waitcnt(0);
    __syncthreads();
    bart += 16;
    if (tid == 0)
      __hip_atomic_fetch_add(ctr, 1u, __ATOMIC_RELEASE, __HIP_MEMORY_SCOPE_AGENT);
  };
  auto barwait = [&]() {
    if (tid == 0) {
      while (__hip_atomic_load(ctr, __ATOMIC_RELAXED, __HIP_MEMORY_SCOPE_AGENT) < bart)
        __builtin_amdgcn_s_sleep(1);
    }
    __syncthreads();
    __asm__ __volatile__("" ::: "memory");
  };

  float4 sv[4];
  auto stage_issue = [&](const float* src) {
#pragma unroll
    for (int j = 0; j < 4; ++j) {
      int slot = j * 1024 + tid;
      asm volatile("global_load_dwordx4 %0, %1, off sc1"
                   : "=v"(sv[j]) : "v"(src + (slot >> 7) * 512 + ((slot & 127) << 2)));
    }
  };
  auto stage_finish = [&](float* dstLDS) {
    asm volatile("s_waitcnt vmcnt(0)" ::: "memory");
#pragma unroll
    for (int j = 0; j < 4; ++j) {
      int slot = j * 1024 + tid;
      *(float4*)(dstLDS + (slot >> 7) * AS + ((slot & 127) << 2)) = sv[j];
    }
    __syncthreads();
  };

  // ---- gh1 gemm: A1 x Whh1 (k4 inner; B [gate][pair][pr][ki4]) ----
  auto gemmP = [&](const float* A, const float* Bp, float (&acc)[2][2][3]) {
    const float* bp = Bp + (unsigned)kh * 12288 + pr * 4;
    const float* ap = A + (unsigned)r0 * AS + kh * 128;
#pragma unroll 4
    for (int k4 = 0; k4 < 32; ++k4) {
      const float* p = bp + (unsigned)k4 * 384;
      float4 b[3][2];
#pragma unroll
      for (int gg = 0; gg < 3; ++gg) {
        b[gg][0] = *(const float4*)(p + gg * 128);
        b[gg][1] = *(const float4*)(p + gg * 128 + 64);
      }
      float4 a0 = *(const float4*)(ap + k4 * 4);
      float4 a1 = *(const float4*)(ap + AS + k4 * 4);
      const float* a0a = (const float*)&a0;
      const float* a1a = (const float*)&a1;
#pragma unroll
      for (int i = 0; i < 4; ++i)
#pragma unroll
        for (int gg = 0; gg < 3; ++gg) {
          const float* bb = (const float*)&b[gg][0];
          const float* bc = (const float*)&b[gg][1];
          acc[0][0][gg] = fmaf(a0a[i], bb[i], acc[0][0][gg]);
          acc[0][1][gg] = fmaf(a1a[i], bb[i], acc[0][1][gg]);
          acc[1][0][gg] = fmaf(a0a[i], bc[i], acc[1][0][gg]);
          acc[1][1][gg] = fmaf(a1a[i], bc[i], acc[1][1][gg]);
        }
    }
  };

  // ---- fused gemm: A0 x [Wih1 | Whh0] -> (aI, aH). B [k2][panel][gate][pr][pair*ki2] ----
  auto gemmF = [&](const float* A, float (&aI)[2][2][3], float (&aH)[2][2][3]) {
    const float* bp = WpF + (unsigned)kh * 24576 + pr * 4;
    const float* ap = A + (unsigned)r0 * AS + kh * 128;
#pragma unroll 2
    for (int k4 = 0; k4 < 32; ++k4) {
      float4 a0 = *(const float4*)(ap + k4 * 4);
      float4 a1 = *(const float4*)(ap + AS + k4 * 4);
      const float* a0a = (const float*)&a0;
      const float* a1a = (const float*)&a1;
#pragma unroll
      for (int h = 0; h < 2; ++h) {
        const float* p = bp + (unsigned)(k4 * 2 + h) * 384;
        float4 bi[3], bh[3];
#pragma unroll
        for (int gg = 0; gg < 3; ++gg) {
          bi[gg] = *(const float4*)(p + gg * 64);
          bh[gg] = *(const float4*)(p + 192 + gg * 64);
        }
        // b vec = (pair0ki0, pair0ki1, pair1ki0, pair1ki1); a index = 2h+ki
#pragma unroll
        for (int ki = 0; ki < 2; ++ki) {
          float av0 = a0a[2 * h + ki], av1 = a1a[2 * h + ki];
#pragma unroll
          for (int gg = 0; gg < 3; ++gg) {
            const float* bia = (const float*)&bi[gg];
            const float* bha = (const float*)&bh[gg];
            aI[0][0][gg] = fmaf(av0, bia[ki], aI[0][0][gg]);
            aI[0][1][gg] = fmaf(av1, bia[ki], aI[0][1][gg]);
            aI[1][0][gg] = fmaf(av0, bia[2 + ki], aI[1][0][gg]);
            aI[1][1][gg] = fmaf(av1, bia[2 + ki], aI[1][1][gg]);
            aH[0][0][gg] = fmaf(av0, bha[ki], aH[0][0][gg]);
            aH[0][1][gg] = fmaf(av1, bha[ki], aH[0][1][gg]);
            aH[1][0][gg] = fmaf(av0, bha[2 + ki], aH[1][0][gg]);
            aH[1][1][gg] = fmaf(av1, bha[2 + ki], aH[1][1][gg]);
          }
        }
      }
    }
  };

  // ---- z gemm: K=64, quarter 16 per kh ----
  auto gemmZ = [&](int t, float (&acc)[2][2][3]) {
    const float* bp = WpT + (unsigned)kh * 1536 + pr * 4;
#pragma unroll
    for (int k4 = 0; k4 < 4; ++k4) {
      const float* p = bp + (unsigned)k4 * 384;
      float4 b[3][2];
#pragma unroll
      for (int gg = 0; gg < 3; ++gg) {
        b[gg][0] = *(const float4*)(p + gg * 128);
        b[gg][1] = *(const float4*)(p + gg * 128 + 64);
      }
      float4 a0 = *(const float4*)(z_temporal + ((unsigned)(b0 + r0) * 128 + t) * 64 + kh * 16 + k4 * 4);
      float4 a1 = *(const float4*)(z_temporal + ((unsigned)(b0 + r0 + 1) * 128 + t) * 64 + kh * 16 + k4 * 4);
      const float* a0a = (const float*)&a0;
      const float* a1a = (const float*)&a1;
#pragma unroll
      for (int i = 0; i < 4; ++i)
#pragma unroll
        for (int gg = 0; gg < 3; ++gg) {
          const float* bb = (const float*)&b[gg][0];
          const float* bc = (const float*)&b[gg][1];
          acc[0][0][gg] = fmaf(a0a[i], bb[i], acc[0][0][gg]);
          acc[0][1][gg] = fmaf(a1a[i], bb[i], acc[0][1][gg]);
          acc[1][0][gg] = fmaf(a0a[i], bc[i], acc[1][0][gg]);
          acc[1][1][gg] = fmaf(a1a[i], bc[i], acc[1][1][gg]);
        }
    }
  };

  // ---- 4-deep reduction ladder: kh0 ends with the full sum ----
  auto reduce4 = [&](float (&a)[2][2][3]) {
    auto wr = [&](int slot) {
#pragma unroll
      for (int p = 0; p < 2; ++p)
#pragma unroll
        for (int r = 0; r < 2; ++r) {
          float* q = Rbuf + slot * (32 * RS) + (r0 + r) * RS + 3 * (pr + 16 * p);
          q[0] = a[p][r][0]; q[1] = a[p][r][1]; q[2] = a[p][r][2];
        }
    };
    auto ad = [&](int slot) {
#pragma unroll
      for (int p = 0; p < 2; ++p)
#pragma unroll
        for (int r = 0; r < 2; ++r) {
          const float* q = Rbuf + slot * (32 * RS) + (r0 + r) * RS + 3 * (pr + 16 * p);
          a[p][r][0] += q[0]; a[p][r][1] += q[1]; a[p][r][2] += q[2];
        }
    };
    __syncthreads();                    // protect Rbuf from previous readers
    if (kh == 1) wr(0);
    if (kh == 3) wr(1);
    __syncthreads();
    if (kh == 0) ad(0);
    if (kh == 2) ad(1);
    __syncthreads();
    if (kh == 2) wr(0);
    __syncthreads();
    if (kh == 0) ad(0);
  };

  // heads for step tp (reads A1 = h1_new(tp)); updates irr_l; writes outputs
  auto do_heads = [&](int tp) {
    const float tsp = (float)tp * (1.0f / 127.0f);
    const float* Ar = A1 + hrow * AS;
    {
      const float* hz = ws + OFF_HWHZ;
      float d0 = 0.0f, d1 = 0.0f;
#pragma unroll
      for (int i = 0; i < 4; ++i) {
        int k = kp * 4 + 128 * i;
        float4 x = *(const float4*)(Ar + k);
        d0 += dot4(x, *(const float4*)(hz + k));
        d1 += dot4(x, *(const float4*)(hz + 516 + k));
      }
#pragma unroll
      for (int off = 1; off < 32; off <<= 1) { d0 += __shfl_xor(d0, off, 32); d1 += __shfl_xor(d1, off, 32); }
      if (kp == 0) {
        float h0v = sigm(d0 + tsp * hz[512] + bhz0);
        float h1v = sigm(d1 + tsp * hz[516 + 512] + bhz1);
        float i0 = irr_l[hrow][0], i1 = irr_l[hrow][1];
        const float* ub = u_bern + ((unsigned)tp * 512 + b0 + hrow) * 2;
        irr_l[hrow][0] = fminf(i0 + ((ub[0] < h0v * (1.0f - i0)) ? 1.0f : 0.0f), 1.0f);
        irr_l[hrow][1] = fminf(i1 + ((ub[1] < h1v * (1.0f - i1)) ? 1.0f : 0.0f), 1.0f);
      }
    }
    if (s < 12) {
      const float* wt = ws + OFF_HWTC + (unsigned)(2 * s) * 512;
      float d0 = 0.0f, d1 = 0.0f;
#pragma unroll
      for (int i = 0; i < 4; ++i) {
        int k = kp * 4 + 128 * i;
        float4 x = *(const float4*)(Ar + k);
        d0 += dot4(x, *(const float4*)(wt + k));
        d1 += dot4(x, *(const float4*)(wt + 512 + k));
      }
#pragma unroll
      for (int off = 1; off < 32; off <<= 1) { d0 += __shfl_xor(d0, off, 32); d1 += __shfl_xor(d1, off, 32); }
      if (kp == 0) {
        int brow = b0 + hrow;
        float msk = (tp < lengths[brow]) ? 1.0f : 0.0f;
        float* o = out + OUT_TC + ((unsigned)brow * 128 + tp) * 24 + 2 * s;
        o[0] = sigm(d0 + b_tc[2 * s]) * msk;
        o[1] = sigm(d1 + b_tc[2 * s + 1]) * msk;
      }
    } else if (s == 15) {
      if (kp == 0) {
        int brow = b0 + hrow;
        float msk = (tp < lengths[brow]) ? 1.0f : 0.0f;
        out[OUT_TCAT + ((unsigned)brow * 128 + tp) * 22 + 6]  = irr_l[hrow][0] * msk;
        out[OUT_TCAT + ((unsigned)brow * 128 + tp) * 22 + 17] = irr_l[hrow][1] * msk;
        out[OUT_VM + (unsigned)brow * 128 + tp] = msk;
        out[OUT_VT + (unsigned)brow * 128 + tp] = tsp;
      }
    } else {
      const int w = (s == 12) ? 6 : (s == 13) ? 10 : 4;
      const float* WT = ws + ((s == 12) ? OFF_HWT0 : (s == 13) ? OFF_HWT2 : OFF_HWT4);
      const float* bt = (s == 12) ? b_tcat0 : (s == 13) ? b_tcat2 : b_tcat4;
      const float* ut = (s == 12) ? u_t0 : (s == 13) ? u_t2 : u_t4;
      const int cbase = (s == 12) ? 0 : (s == 13) ? 7 : 18;
      float lg[10];
#pragma unroll
      for (int c = 0; c < 10; ++c) lg[c] = 0.0f;
#pragma unroll
      for (int i = 0; i < 4; ++i) {
        int k = kp * 4 + 128 * i;
        float4 x = *(const float4*)(Ar + k);
        for (int c = 0; c < w; ++c)
          lg[c] += dot4(x, *(const float4*)(WT + (unsigned)c * 512 + k));
      }
      for (int c = 0; c < w; ++c) {
#pragma unroll
        for (int off = 1; off < 32; off <<= 1) lg[c] += __shfl_xor(lg[c], off, 32);
      }
      if (kp == 0) {
        int brow = b0 + hrow;
        float msk = (tp < lengths[brow]) ? 1.0f : 0.0f;
        float e[10], mx = -1e30f;
        for (int c = 0; c < w; ++c) {
          float uu = ut[((unsigned)tp * 512 + brow) * (unsigned)w + c];
          e[c] = lg[c] + bt[c] + gumb(uu); mx = fmaxf(mx, e[c]);
        }
        float sum = 0.0f;
        for (int c = 0; c < w; ++c) { e[c] = expf(e[c] - mx); sum += e[c]; }
        float inv = 1.0f / sum;
        float* o = out + OUT_TCAT + ((unsigned)brow * 128 + tp) * 22 + cbase;
        for (int c = 0; c < w; ++c) o[c] = e[c] * inv * msk;
      }
    }
    __syncthreads();   // irr_l visible before cell0
  };

  // rotated pipeline: accH = gh0(t) partials (from prev iter's fused gemm);
  // accZ = zt(t) partials (from prev iter's post-b2 slot).
  float accH[2][2][3] = {};      // t=0: h0_prev = 0
  float accZ[2][2][3] = {};
  gemmZ(0, accZ);                // prologue

  for (int t = 0; t < 128; ++t) {
    const float tsv = (float)t * (1.0f / 127.0f);

    // 1. finish h1_new(t-1) -> A1; heads(t-1)
    if (t > 0) {
      stage_finish(A1);
      do_heads(t - 1);
    }

    // 2. reduce gh0 + z partials
    reduce4(accH);
    reduce4(accZ);

    // 3. cell0 (kh0 lanes), write h0_new
    if (kh == 0) {
#pragma unroll
      for (int p = 0; p < 2; ++p) {
        int u = pr + 16 * p, jg = s * 32 + u;
        float4 cw = *(const float4*)(cellc + u * 20);       // wts0,1,2, wi00
        float4 ci = *(const float4*)(cellc + u * 20 + 4);   // wi01,wi02,wi10,wi11
        float4 cb = *(const float4*)(cellc + u * 20 + 8);   // wi12, bh0r,z,n
#pragma unroll
        for (int r = 0; r < 2; ++r) {
          int row = r0 + r;
          float4 g0 = *(const float4*)(gi0p + ((unsigned)row * 32 + u) * 4);
          float i0 = irr_l[row][0], i1 = irr_l[row][1];
          float gir = accZ[p][r][0] + g0.x + tsv * cw.x + i0 * cw.w + i1 * ci.z;
          float giz = accZ[p][r][1] + g0.y + tsv * cw.y + i0 * ci.x + i1 * ci.w;
          float gin = accZ[p][r][2] + g0.z + tsv * cw.z + i0 * ci.y + i1 * cb.x;
          float rr = sigm(gir + accH[p][r][0] + cb.y);
          float zz = sigm(giz + accH[p][r][1] + cb.z);
          float nn = tanhf(gin + rr * (accH[p][r][2] + cb.w));
          float hp = A0[row * AS + jg];
          astore(h0x + (unsigned)(b0 + row) * 512 + jg, (1.0f - zz) * nn + zz * hp);
        }
      }
    }

    // 4-6. arrive b1; gh1 gemm (A1 = h1_prev); wait b1
    barrive();
    float accH2[2][2][3] = {};
    gemmP(A1, WpH, accH2);
    barwait();
    reduce4(accH2);

    // 7. stage h0_new -> A0
    stage_issue(h0x + b0 * 512);
    stage_finish(A0);

    // 8. fused gemm: gi1(t) + gh0(t+1), one A0 pass
    float accI2[2][2][3] = {};
#pragma unroll
    for (int p = 0; p < 2; ++p)
#pragma unroll
      for (int r = 0; r < 2; ++r) { accH[p][r][0] = accH[p][r][1] = accH[p][r][2] = 0.0f; }
    gemmF(A0, accI2, accH);
    reduce4(accI2);

    // 9. cell1 (kh0 lanes), write h1_new
    if (kh == 0) {
#pragma unroll
      for (int p = 0; p < 2; ++p) {
        int u = pr + 16 * p, jg = s * 32 + u;
        float4 cc = *(const float4*)(cellc + u * 20 + 12);  // bi1r,z,n, bh1r
        float4 cd = *(const float4*)(cellc + u * 20 + 16);  // bh1z, bh1n, pad, pad
#pragma unroll
        for (int r = 0; r < 2; ++r) {
          int row = r0 + r;
          float rr = sigm(accI2[p][r][0] + cc.x + accH2[p][r][0] + cc.w);
          float zz = sigm(accI2[p][r][1] + cc.y + accH2[p][r][1] + cd.x);
          float nn = tanhf(accI2[p][r][2] + cc.z + rr * (accH2[p][r][2] + cd.y));
          float hp = A1[row * AS + jg];
          astore(h1x + (unsigned)(b0 + row) * 512 + jg, (1.0f - zz) * nn + zz * hp);
        }
      }
    }

    // 10-12. arrive b2; z gemm(t+1) covers the wait; wait b2
    barrive();
#pragma unroll
    for (int p = 0; p < 2; ++p)
#pragma unroll
      for (int r = 0; r < 2; ++r) { accZ[p][r][0] = accZ[p][r][1] = accZ[p][r][2] = 0.0f; }
    if (t < 127) gemmZ(t + 1, accZ);
    barwait();

    // 13. issue h1_new -> A1 stage (drained next iter)
    stage_issue(h1x + b0 * 512);
  }
  stage_finish(A1);
  do_heads(127);
}

// ---------------- launcher ----------------
extern "C" void kernel_launch(void* const* d_in, const int* in_sizes, int n_in,
                              void* d_out, int out_size, void* d_ws, size_t ws_size,
                              hipStream_t stream) {
  const float* z_static   = (const float*)d_in[0];
  const float* z_temporal = (const float*)d_in[1];
  const int*   lengths    = (const int*)d_in[2];
  const float* Ws1 = (const float*)d_in[3];
  const float* bs1 = (const float*)d_in[4];
  const float* Ws2 = (const float*)d_in[5];
  const float* bs2 = (const float*)d_in[6];
  const float* W_sc = (const float*)d_in[7];
  const float* b_sc = (const float*)d_in[8];
  const float* W_cat0 = (const float*)d_in[9];
  const float* b_cat0 = (const float*)d_in[10];
  const float* W_cat1 = (const float*)d_in[11];
  const float* b_cat1 = (const float*)d_in[12];
  const float* W_cat2 = (const float*)d_in[13];
  const float* b_cat2 = (const float*)d_in[14];
  const float* W_irr = (const float*)d_in[15];
  const float* b_irr = (const float*)d_in[16];
  const float* Wih0 = (const float*)d_in[17];
  const float* Whh0 = (const float*)d_in[18];
  const float* bih0 = (const float*)d_in[19];
  const float* bhh0 = (const float*)d_in[20];
  const float* Wih1 = (const float*)d_in[21];
  const float* Whh1 = (const float*)d_in[22];
  const float* bih1 = (const float*)d_in[23];
  const float* bhh1 = (const float*)d_in[24];
  const float* W_tc = (const float*)d_in[25];
  const float* b_tc = (const float*)d_in[26];
  const float* W_tcat0 = (const float*)d_in[27];
  const float* b_tcat0 = (const float*)d_in[28];
  const float* W_tcat2 = (const float*)d_in[29];
  const float* b_tcat2 = (const float*)d_in[30];
  const float* W_tcat4 = (const float*)d_in[31];
  const float* b_tcat4 = (const float*)d_in[32];
  const float* W_hz = (const float*)d_in[33];
  const float* b_hz = (const float*)d_in[34];
  const float* u_sc0 = (const float*)d_in[35];
  const float* u_sc1 = (const float*)d_in[36];
  const float* u_sc2 = (const float*)d_in[37];
  const float* u_irr = (const float*)d_in[38];
  const float* u_t0 = (const float*)d_in[39];
  const float* u_t2 = (const float*)d_in[40];
  const float* u_t4 = (const float*)d_in[41];
  const float* u_bern = (const float*)d_in[42];

  float* ws = (float*)d_ws;
  float* out = (float*)d_out;

  hipMemsetAsync((void*)(ws + OFF_CTR), 0, (size_t)(OFF_END - OFF_CTR) * sizeof(float), stream);

  pack_kernel<<<12805, 256, 0, stream>>>(Wih0, Whh0, Wih1, Whh1,
      bhh0, bih1, bhh1, W_tc, W_hz, W_tcat0, W_tcat2, W_tcat4, ws);
  mlp_kernel<128><<<128, 256, 0, stream>>>(z_static, Ws1, bs1, ws + OFF_HID);
  mlp_kernel<512><<<128, 256, 0, stream>>>(ws + OFF_HID, Ws2, bs2, ws + OFF_BASE);
  static_heads_kernel<<<512, 64, 0, stream>>>(ws + OFF_BASE, W_sc, b_sc,
      W_cat0, b_cat0, W_cat1, b_cat1, W_cat2, b_cat2, W_irr, b_irr,
      u_sc0, u_sc1, u_sc2, u_irr, out, ws + OFF_IRR0);
  gi0_kernel<<<128, 256, 0, stream>>>(ws + OFF_BASE, ws + OFF_WMIDP, bih0, ws + OFF_GI0S);
  recurrence_kernel<<<256, 1024, 0, stream>>>(ws, z_temporal, lengths,
      b_tc, b_hz, b_tcat0, b_tcat2, b_tcat4,
      u_t0, u_t2, u_t4, u_bern, out);
}